// Round 15
// baseline (768.115 us; speedup 1.0000x reference)
//
#include <hip/hip_runtime.h>
#include <hip/hip_bf16.h>
#include <math.h>

// GCN: h1 = relu(Agg(x@W1) + b1); h2 = relu(Agg(h1@W2) + b2);
// out[g] = mean_pool(h2)[g] @ Wf + bf
// R4: wave-sliced pool. R5: decoupled scan. R6: k_agg unroll x4.
// R7: bf16 feature table. R8: k_fill role-partitioned. R9/R10: MFMA linear.
// R13: reverted R12 lane-split agg (regressed). R14: NT loads FAILED
//   (WRITE still 66MB, FETCH rose to 54MB) -> reverted.
// R15: role = REAL XCD id (s_getreg HW_REG_XCC_ID, m09-verified) + ticket
//   work-stealing. Tests theory that blockIdx%8 != XCD mapping, which left
//   fill/col lines shared by all 8 incoherent L2s (atomic ping-pong latency
//   + partial-line write amp). Rescue phase preserves correctness under ANY
//   dispatch (G16). Applied to k_fill AND k_degcount.

#define DFEAT 128
#define SCAN_NB 256
#define SCAN_TPB 256
#define FILL_CHUNKS 256

typedef unsigned int uint32;
typedef __attribute__((ext_vector_type(8))) short bf16x8;
typedef __attribute__((ext_vector_type(4))) float f32x4;

__device__ __forceinline__ uint32 f2bf_rne(float f) {
    uint32 x = __float_as_uint(f);
    return (x + 0x7fffu + ((x >> 16) & 1u)) >> 16;
}
__device__ __forceinline__ uint32 packbf2(float lo, float hi) {
    return f2bf_rne(lo) | (f2bf_rne(hi) << 16);
}
__device__ __forceinline__ float bflo(uint32 u) { return __uint_as_float(u << 16); }
__device__ __forceinline__ float bfhi(uint32 u) { return __uint_as_float(u & 0xffff0000u); }

__device__ __forceinline__ int xcc_id() {
    int x;
    asm volatile("s_getreg_b32 %0, hwreg(HW_REG_XCC_ID)" : "=s"(x));
    return x & 7;
}

__global__ void k_zero2(int* __restrict__ a, int* __restrict__ b, int n) {
    int i = blockIdx.x * blockDim.x + threadIdx.x;
    if (i < n) { a[i] = 0; b[i] = 0; }
}

__global__ void k_zero_f(float* __restrict__ p, int n) {
    int i = blockIdx.x * blockDim.x + threadIdx.x;
    if (i < n) p[i] = 0.f;
}

// Degree count, XCD-role ticketed: blocks count edges whose dst range belongs
// to their own XCD; degcnt lines stay in one L2. Rescue loop guarantees
// completion under any block->XCD mapping.
__global__ __launch_bounds__(256) void k_degcount(const int* __restrict__ dst,
                                                  int* __restrict__ degcnt,
                                                  int* __restrict__ tickets, int E) {
    int myr = xcc_id();
    int per = (E + FILL_CHUNKS - 1) / FILL_CHUNKS;
    __shared__ int chunkS;
    for (int rr = 0; rr < 8; ++rr) {
        int role = (myr + rr) & 7;
        for (;;) {
            if (threadIdx.x == 0) chunkS = atomicAdd(&tickets[role], 1);
            __syncthreads();
            int c = chunkS;
            __syncthreads();
            if (c >= FILL_CHUNKS) break;
            int beg = c * per, end = min(E, beg + per);
            for (int e = beg + threadIdx.x; e < end; e += 256) {
                int d = dst[e];
                if (((d >> 9) & 7) == role) atomicAdd(&degcnt[d], 1);
            }
        }
    }
}

// W[k][n] f32 -> Wt[n][k] bf16 (one-time, 16K elements)
__global__ __launch_bounds__(256) void k_wt(const float* __restrict__ W,
                                            unsigned short* __restrict__ Wt) {
    int idx = blockIdx.x * 256 + threadIdx.x;
    if (idx < 128 * 128) {
        int n = idx >> 7, k = idx & 127;
        Wt[idx] = (unsigned short)f2bf_rne(W[(k << 7) + n]);
    }
}

// Scan phase 1
__global__ __launch_bounds__(SCAN_TPB) void k_partsum(const int* __restrict__ deg,
                                                      int* __restrict__ bsum,
                                                      int N, int chunk) {
    int b = blockIdx.x, tid = threadIdx.x;
    int beg = b * chunk, end = min(N, beg + chunk);
    int s = 0;
    for (int i = beg + tid; i < end; i += SCAN_TPB) s += deg[i];
    __shared__ int lds[SCAN_TPB];
    lds[tid] = s;
    __syncthreads();
    for (int off = SCAN_TPB / 2; off > 0; off >>= 1) {
        if (tid < off) lds[tid] += lds[tid + off];
        __syncthreads();
    }
    if (tid == 0) bsum[b] = lds[0];
}

// Scan phase 2
__global__ __launch_bounds__(SCAN_NB) void k_scanb(int* __restrict__ bsum) {
    __shared__ int lds[SCAN_NB];
    int tid = threadIdx.x;
    int v = bsum[tid];
    lds[tid] = v;
    __syncthreads();
    for (int off = 1; off < SCAN_NB; off <<= 1) {
        int t = (tid >= off) ? lds[tid - off] : 0;
        __syncthreads();
        lds[tid] += t;
        __syncthreads();
    }
    bsum[tid] = lds[tid] - v;  // exclusive base
}

// Scan phase 3: write rowptr + dinv
__global__ __launch_bounds__(SCAN_TPB) void k_writeptr(const int* __restrict__ deg,
                                                       const int* __restrict__ bbase,
                                                       int* __restrict__ rowptr,
                                                       float* __restrict__ dinv,
                                                       int N, int chunk) {
    int b = blockIdx.x, tid = threadIdx.x;
    int beg = b * chunk, end = min(N, beg + chunk);
    int per = (chunk + SCAN_TPB - 1) / SCAN_TPB;
    int tbeg = beg + tid * per;
    int tend = min(end, tbeg + per);
    int s = 0;
    for (int i = tbeg; i < tend; ++i) s += deg[i];
    __shared__ int lds[SCAN_TPB];
    lds[tid] = s;
    __syncthreads();
    for (int off = 1; off < SCAN_TPB; off <<= 1) {
        int t = (tid >= off) ? lds[tid - off] : 0;
        __syncthreads();
        lds[tid] += t;
        __syncthreads();
    }
    int run = bbase[b] + ((tid == 0) ? 0 : lds[tid - 1]);
    for (int i = tbeg; i < tend; ++i) {
        int d = deg[i];
        rowptr[i] = run;
        dinv[i] = rsqrtf((float)(d + 1));  // +1 self-loop
        run += d;
    }
    if (tend == N && tbeg < tend) rowptr[N] = run;  // == E
}

// CSR fill, XCD-role ticketed (R15): same role logic as k_degcount; col and
// fill[] lines are written only from one XCD's L2.
__global__ __launch_bounds__(256) void k_fill(const int* __restrict__ src,
                                              const int* __restrict__ dst,
                                              const int* __restrict__ rowptr,
                                              int* __restrict__ fill,
                                              int* __restrict__ col,
                                              int* __restrict__ tickets, int E) {
    int myr = xcc_id();
    int per = (E + FILL_CHUNKS - 1) / FILL_CHUNKS;
    __shared__ int chunkS;
    for (int rr = 0; rr < 8; ++rr) {
        int role = (myr + rr) & 7;
        for (;;) {
            if (threadIdx.x == 0) chunkS = atomicAdd(&tickets[role], 1);
            __syncthreads();
            int c = chunkS;
            __syncthreads();
            if (c >= FILL_CHUNKS) break;
            int beg = c * per, end = min(E, beg + per);
            for (int e = beg + threadIdx.x; e < end; e += 256) {
                int d = dst[e];
                if (((d >> 9) & 7) == role) {
                    int pos = rowptr[d] + atomicAdd(&fill[d], 1);
                    col[pos] = src[e];
                }
            }
        }
    }
}

// C[N,128](bf16) = H[N,128](f32) @ W via Wt[n][k] bf16. MFMA 16x16x32.
__global__ __launch_bounds__(256, 3) void k_linear_mfma(const float* __restrict__ H,
                                                        const uint32* __restrict__ Wt,
                                                        uint32* __restrict__ C,
                                                        int N, int ntiles) {
    __shared__ uint32 WtS[128 * 64];  // 32 KB
    __shared__ uint32 inS[64 * 64];   // 16 KB
    int tid = threadIdx.x;
    int lane = tid & 63;
    int wv = tid >> 6;
    int g = lane >> 4;
    int r = lane & 15;
    int swz = (r & 7) << 4;
    {   // stage Wt -> LDS: 2048 uint4 chunks, 16 per 256B row
        const uint4* srcp = (const uint4*)Wt;
#pragma unroll
        for (int i = 0; i < 8; ++i) {
            int c = tid + i * 256;
            int n = c >> 4, off = c & 15;
            int b = (n * 256 + off * 16) ^ ((n & 7) << 4);
            *(uint4*)((char*)WtS + b) = srcp[c];
        }
    }
    for (int t = blockIdx.x; t < ntiles; t += gridDim.x) {
        int rbase = t << 6;
        __syncthreads();
        {   // stage 64 H rows f32 -> bf16, swizzled
            const float4* H4 = (const float4*)(H + (size_t)rbase * DFEAT);
            int limrow = N - rbase;
#pragma unroll
            for (int i = 0; i < 4; ++i) {
                int c = tid + i * 256;
                int m = c >> 4, off = c & 15;
                uint4 w2 = make_uint4(0u, 0u, 0u, 0u);
                if (m < limrow) {
                    float4 f0 = H4[m * 32 + off * 2];
                    float4 f1 = H4[m * 32 + off * 2 + 1];
                    w2.x = packbf2(f0.x, f0.y); w2.y = packbf2(f0.z, f0.w);
                    w2.z = packbf2(f1.x, f1.y); w2.w = packbf2(f1.z, f1.w);
                }
                int b = (m * 256 + off * 16) ^ ((m & 7) << 4);
                *(uint4*)((char*)inS + b) = w2;
            }
        }
        __syncthreads();
        f32x4 acc[8];
#pragma unroll
        for (int nt = 0; nt < 8; ++nt) acc[nt] = (f32x4){0.f, 0.f, 0.f, 0.f};
        int mrow = wv * 16 + r;
        const char* inB = (const char*)inS + mrow * 256;
#pragma unroll
        for (int kk = 0; kk < 4; ++kk) {
            int koff = (kk * 64 + g * 16) ^ swz;
            bf16x8 bfrag = *(const bf16x8*)(inB + koff);
#pragma unroll
            for (int nt = 0; nt < 8; ++nt) {
                bf16x8 afrag = *(const bf16x8*)((const char*)WtS + (nt * 16 + r) * 256 + koff);
                acc[nt] = __builtin_amdgcn_mfma_f32_16x16x32_bf16(afrag, bfrag, acc[nt], 0, 0, 0);
            }
        }
        int m = rbase + mrow;
        if (m < N) {
            uint2* Crow = (uint2*)(C + (size_t)m * 64);
#pragma unroll
            for (int nt = 0; nt < 8; ++nt) {
                uint2 u;
                u.x = packbf2(acc[nt].x, acc[nt].y);
                u.y = packbf2(acc[nt].z, acc[nt].w);
                Crow[nt * 4 + g] = u;
            }
        }
    }
}

// Pull aggregation (R11 form): one 64-lane wave per node; lane holds features
// 2*lane,2*lane+1; x4 unroll = 4 gathers in flight; f32 accum.
__global__ __launch_bounds__(256) void k_agg(const uint32* __restrict__ Tb,
                                             float2* __restrict__ Hout,
                                             const int* __restrict__ col,
                                             const int* __restrict__ rowptr,
                                             const float* __restrict__ dinv,
                                             const float* __restrict__ bias, int N) {
    int lane = threadIdx.x & 63;
    int node = blockIdx.x * 4 + (threadIdx.x >> 6);
    if (node >= N) return;
    float2 b = ((const float2*)bias)[lane];
    float di = dinv[node];
    uint32 us = Tb[(size_t)node * 64 + lane];
    float ws = di * di;
    float2 acc;
    acc.x = bflo(us) * ws;
    acc.y = bfhi(us) * ws;
    int beg = rowptr[node], end = rowptr[node + 1];
    int j = beg;
    for (; j + 3 < end; j += 4) {
        int s0 = col[j + 0];
        int s1 = col[j + 1];
        int s2 = col[j + 2];
        int s3 = col[j + 3];
        float w0 = dinv[s0] * di;
        float w1 = dinv[s1] * di;
        float w2 = dinv[s2] * di;
        float w3 = dinv[s3] * di;
        uint32 u0 = Tb[(size_t)s0 * 64 + lane];
        uint32 u1 = Tb[(size_t)s1 * 64 + lane];
        uint32 u2 = Tb[(size_t)s2 * 64 + lane];
        uint32 u3 = Tb[(size_t)s3 * 64 + lane];
        acc.x += w0 * bflo(u0); acc.y += w0 * bfhi(u0);
        acc.x += w1 * bflo(u1); acc.y += w1 * bfhi(u1);
        acc.x += w2 * bflo(u2); acc.y += w2 * bfhi(u2);
        acc.x += w3 * bflo(u3); acc.y += w3 * bfhi(u3);
    }
    for (; j < end; ++j) {
        int s = col[j];
        float w = dinv[s] * di;
        uint32 u = Tb[(size_t)s * 64 + lane];
        acc.x += w * bflo(u);
        acc.y += w * bfhi(u);
    }
    acc.x = fmaxf(acc.x + b.x, 0.f);
    acc.y = fmaxf(acc.y + b.y, 0.f);
    Hout[(size_t)node * 64 + lane] = acc;
}

// Pool phase 1: wave-sliced partial sums, atomic flush at graph boundaries.
__global__ __launch_bounds__(256) void k_pool_sum(const float2* __restrict__ Hn,
                                                  const int* __restrict__ batch,
                                                  float* __restrict__ gsum,
                                                  int N, int waves_total) {
    int w = blockIdx.x * 4 + (threadIdx.x >> 6);
    int lane = threadIdx.x & 63;
    int per = (N + waves_total - 1) / waves_total;
    int n0 = w * per;
    int n1 = min(N, n0 + per);
    if (n0 >= n1) return;
    int gcur = batch[n0];
    float2 acc = make_float2(0.f, 0.f);
    for (int i = n0; i < n1; ++i) {
        int g = batch[i];
        if (g != gcur) {
            atomicAdd(&gsum[gcur * DFEAT + lane * 2 + 0], acc.x);
            atomicAdd(&gsum[gcur * DFEAT + lane * 2 + 1], acc.y);
            acc = make_float2(0.f, 0.f);
            gcur = g;
        }
        float2 v = Hn[(size_t)i * 64 + lane];
        acc.x += v.x;
        acc.y += v.y;
    }
    atomicAdd(&gsum[gcur * DFEAT + lane * 2 + 0], acc.x);
    atomicAdd(&gsum[gcur * DFEAT + lane * 2 + 1], acc.y);
}

// Pool phase 2: divide by count, dot Wf, +bf.
__global__ __launch_bounds__(128) void k_head(const float* __restrict__ gsum,
                                              const int* __restrict__ batch,
                                              const float* __restrict__ Wf,
                                              const float* __restrict__ bf,
                                              float* __restrict__ out, int N) {
    int g = blockIdx.x;
    int tid = threadIdx.x;
    int l = 0, h = N;
    while (l < h) { int m = (l + h) >> 1; if (batch[m] < g) l = m + 1; else h = m; }
    int lo = l;
    h = N;
    while (l < h) { int m = (l + h) >> 1; if (batch[m] < g + 1) l = m + 1; else h = m; }
    int hi = l;
    float cnt = (float)((hi - lo) > 0 ? (hi - lo) : 1);
    float val = (gsum[g * DFEAT + tid] / cnt) * Wf[tid];
    for (int off = 32; off >= 1; off >>= 1) val += __shfl_down(val, off, 64);
    __shared__ float ws2[2];
    if ((tid & 63) == 0) ws2[tid >> 6] = val;
    __syncthreads();
    if (tid == 0) out[g] = ws2[0] + ws2[1] + bf[0];
}

extern "C" void kernel_launch(void* const* d_in, const int* in_sizes, int n_in,
                              void* d_out, int out_size, void* d_ws, size_t ws_size,
                              hipStream_t stream) {
    const float* x    = (const float*)d_in[0];
    const int*   ei   = (const int*)d_in[1];
    const int*   batch= (const int*)d_in[2];
    const float* W1   = (const float*)d_in[3];
    const float* b1   = (const float*)d_in[4];
    const float* W2   = (const float*)d_in[5];
    const float* b2   = (const float*)d_in[6];
    const float* Wf   = (const float*)d_in[7];
    const float* bf   = (const float*)d_in[8];

    int N = in_sizes[0] / DFEAT;
    int E = in_sizes[1] / 2;
    int G = out_size;  // num_graphs

    const int* src = ei;
    const int* dst = ei + E;

    char* wsb = (char*)d_ws;
    size_t off = 0;
    auto walloc = [&](size_t bytes) {
        void* p = wsb + off;
        off = (off + bytes + 255) & ~(size_t)255;
        return p;
    };
    uint32* A     = (uint32*)walloc((size_t)N * 64 * sizeof(uint32)); // bf16 table, 25.6 MB
    float* B      = (float*)walloc((size_t)N * DFEAT * sizeof(float)); // 51.2 MB
    float* dinv   = (float*)walloc((size_t)N * sizeof(float));
    int*   rowptr = (int*)  walloc((size_t)(N + 1) * sizeof(int));
    int*   col    = (int*)  walloc((size_t)E * sizeof(int));           // 6.4 MB
    int*   degcnt = (int*)  walloc((size_t)N * sizeof(int));
    int*   fill   = (int*)  walloc((size_t)N * sizeof(int));
    float* gsum   = (float*)walloc((size_t)G * DFEAT * sizeof(float)); // 32 KB (256B-mult)
    int*   tickets= (int*)  walloc(16 * sizeof(int));  // [0..7] degcount, [8..15] fill
    int*   bsum   = (int*)  walloc((size_t)SCAN_NB * sizeof(int));
    unsigned short* Wt1 = (unsigned short*)walloc(128 * 128 * sizeof(unsigned short));
    unsigned short* Wt2 = (unsigned short*)walloc(128 * 128 * sizeof(unsigned short));
    (void)ws_size; (void)n_in;

    int gN = (N + 255) / 256;
    int chunk = (N + SCAN_NB - 1) / SCAN_NB;
    int ntiles = (N + 63) >> 6;

    // CSR build + weight transposes
    k_zero2<<<gN, 256, 0, stream>>>(degcnt, fill, N);
    k_zero_f<<<(G * DFEAT + 16 + 255) / 256, 256, 0, stream>>>(gsum, G * DFEAT + 16); // gsum + tickets (contiguous)
    k_wt<<<64, 256, 0, stream>>>(W1, Wt1);
    k_wt<<<64, 256, 0, stream>>>(W2, Wt2);
    k_degcount<<<2048, 256, 0, stream>>>(dst, degcnt, tickets, E);
    k_partsum<<<SCAN_NB, SCAN_TPB, 0, stream>>>(degcnt, bsum, N, chunk);
    k_scanb<<<1, SCAN_NB, 0, stream>>>(bsum);
    k_writeptr<<<SCAN_NB, SCAN_TPB, 0, stream>>>(degcnt, bsum, rowptr, dinv, N, chunk);
    k_fill<<<2048, 256, 0, stream>>>(src, dst, rowptr, fill, col, tickets + 8, E);

    // layer 1
    k_linear_mfma<<<768, 256, 0, stream>>>(x, (const uint32*)Wt1, A, N, ntiles);
    k_agg<<<(N + 3) / 4, 256, 0, stream>>>(A, (float2*)B, col, rowptr, dinv, b1, N);
    // layer 2
    k_linear_mfma<<<768, 256, 0, stream>>>(B, (const uint32*)Wt2, A, N, ntiles);
    k_agg<<<(N + 3) / 4, 256, 0, stream>>>(A, (float2*)B, col, rowptr, dinv, b2, N);

    // pool + head
    const int POOL_BLOCKS = 1024;
    k_pool_sum<<<POOL_BLOCKS, 256, 0, stream>>>((const float2*)B, batch, gsum, N, POOL_BLOCKS * 4);
    k_head<<<G, 128, 0, stream>>>(gsum, batch, Wf, bf, (float*)d_out, N);
}

// Round 16
// 360.684 us; speedup vs baseline: 2.1296x; 2.1296x over previous
//
#include <hip/hip_runtime.h>
#include <hip/hip_bf16.h>
#include <math.h>

// GCN: h1 = relu(Agg(x@W1) + b1); h2 = relu(Agg(h1@W2) + b2);
// out[g] = mean_pool(h2)[g] @ Wf + bf
// R4: wave-sliced pool. R5: decoupled scan. R6: k_agg unroll x4.
// R7: bf16 feature table. R8: k_fill %8-role partition. R9/R10: MFMA linear.
// R13/R14/R15 post-mortems: lane-split agg, NT loads, XCD-id ticketing ALL
//   regressed -> reverted to R11 forms (k_fill write-amp is structural).
// R16: B buffer bf16 (h1 was already bf16-quantized in linear staging -> no
//   new error on linear path; only pool reads h2 in bf16). Saves ~125 MB:
//   agg writes 50->25 MB x2, linear-2 read 51->26, pool read 51->26.

#define DFEAT 128
#define SCAN_NB 256
#define SCAN_TPB 256
#define FILL_CHUNKS 256

typedef unsigned int uint32;
typedef __attribute__((ext_vector_type(8))) short bf16x8;
typedef __attribute__((ext_vector_type(4))) float f32x4;

__device__ __forceinline__ uint32 f2bf_rne(float f) {
    uint32 x = __float_as_uint(f);
    return (x + 0x7fffu + ((x >> 16) & 1u)) >> 16;
}
__device__ __forceinline__ uint32 packbf2(float lo, float hi) {
    return f2bf_rne(lo) | (f2bf_rne(hi) << 16);
}
__device__ __forceinline__ float bflo(uint32 u) { return __uint_as_float(u << 16); }
__device__ __forceinline__ float bfhi(uint32 u) { return __uint_as_float(u & 0xffff0000u); }

__global__ void k_zero2(int* __restrict__ a, int* __restrict__ b, int n) {
    int i = blockIdx.x * blockDim.x + threadIdx.x;
    if (i < n) { a[i] = 0; b[i] = 0; }
}

__global__ void k_zero_f(float* __restrict__ p, int n) {
    int i = blockIdx.x * blockDim.x + threadIdx.x;
    if (i < n) p[i] = 0.f;
}

__global__ void k_degcount(const int* __restrict__ dst, int* __restrict__ degcnt, int E) {
    int e = blockIdx.x * blockDim.x + threadIdx.x;
    if (e < E) atomicAdd(&degcnt[dst[e]], 1);
}

// W[k][n] f32 -> Wt[n][k] bf16 (one-time, 16K elements)
__global__ __launch_bounds__(256) void k_wt(const float* __restrict__ W,
                                            unsigned short* __restrict__ Wt) {
    int idx = blockIdx.x * 256 + threadIdx.x;
    if (idx < 128 * 128) {
        int n = idx >> 7, k = idx & 127;
        Wt[idx] = (unsigned short)f2bf_rne(W[(k << 7) + n]);
    }
}

// Scan phase 1
__global__ __launch_bounds__(SCAN_TPB) void k_partsum(const int* __restrict__ deg,
                                                      int* __restrict__ bsum,
                                                      int N, int chunk) {
    int b = blockIdx.x, tid = threadIdx.x;
    int beg = b * chunk, end = min(N, beg + chunk);
    int s = 0;
    for (int i = beg + tid; i < end; i += SCAN_TPB) s += deg[i];
    __shared__ int lds[SCAN_TPB];
    lds[tid] = s;
    __syncthreads();
    for (int off = SCAN_TPB / 2; off > 0; off >>= 1) {
        if (tid < off) lds[tid] += lds[tid + off];
        __syncthreads();
    }
    if (tid == 0) bsum[b] = lds[0];
}

// Scan phase 2
__global__ __launch_bounds__(SCAN_NB) void k_scanb(int* __restrict__ bsum) {
    __shared__ int lds[SCAN_NB];
    int tid = threadIdx.x;
    int v = bsum[tid];
    lds[tid] = v;
    __syncthreads();
    for (int off = 1; off < SCAN_NB; off <<= 1) {
        int t = (tid >= off) ? lds[tid - off] : 0;
        __syncthreads();
        lds[tid] += t;
        __syncthreads();
    }
    bsum[tid] = lds[tid] - v;  // exclusive base
}

// Scan phase 3: write rowptr + dinv
__global__ __launch_bounds__(SCAN_TPB) void k_writeptr(const int* __restrict__ deg,
                                                       const int* __restrict__ bbase,
                                                       int* __restrict__ rowptr,
                                                       float* __restrict__ dinv,
                                                       int N, int chunk) {
    int b = blockIdx.x, tid = threadIdx.x;
    int beg = b * chunk, end = min(N, beg + chunk);
    int per = (chunk + SCAN_TPB - 1) / SCAN_TPB;
    int tbeg = beg + tid * per;
    int tend = min(end, tbeg + per);
    int s = 0;
    for (int i = tbeg; i < tend; ++i) s += deg[i];
    __shared__ int lds[SCAN_TPB];
    lds[tid] = s;
    __syncthreads();
    for (int off = 1; off < SCAN_TPB; off <<= 1) {
        int t = (tid >= off) ? lds[tid - off] : 0;
        __syncthreads();
        lds[tid] += t;
        __syncthreads();
    }
    int run = bbase[b] + ((tid == 0) ? 0 : lds[tid - 1]);
    for (int i = tbeg; i < tend; ++i) {
        int d = deg[i];
        rowptr[i] = run;
        dinv[i] = rsqrtf((float)(d + 1));  // +1 self-loop
        run += d;
    }
    if (tend == N && tbeg < tend) rowptr[N] = run;  // == E
}

// CSR fill, %8-role partitioned (R8/R11 proven form).
__global__ __launch_bounds__(256) void k_fill(const int* __restrict__ src,
                                              const int* __restrict__ dst,
                                              const int* __restrict__ rowptr,
                                              int* __restrict__ fill,
                                              int* __restrict__ col, int E) {
    int r = blockIdx.x & 7;
    int chunk = blockIdx.x >> 3;
    int per = (E + FILL_CHUNKS - 1) / FILL_CHUNKS;
    int beg = chunk * per;
    int end = min(E, beg + per);
    for (int e = beg + threadIdx.x; e < end; e += 256) {
        int d = dst[e];
        if (((d >> 9) & 7) == r) {
            int pos = rowptr[d] + atomicAdd(&fill[d], 1);
            col[pos] = src[e];
        }
    }
}

// Layer-1 linear: C[N,128](bf16) = H[N,128](f32) @ Wt. MFMA 16x16x32.
__global__ __launch_bounds__(256, 3) void k_linear_mfma(const float* __restrict__ H,
                                                        const uint32* __restrict__ Wt,
                                                        uint32* __restrict__ C,
                                                        int N, int ntiles) {
    __shared__ uint32 WtS[128 * 64];  // 32 KB
    __shared__ uint32 inS[64 * 64];   // 16 KB
    int tid = threadIdx.x;
    int lane = tid & 63;
    int wv = tid >> 6;
    int g = lane >> 4;
    int r = lane & 15;
    int swz = (r & 7) << 4;
    {   // stage Wt -> LDS: 2048 uint4 chunks, 16 per 256B row
        const uint4* srcp = (const uint4*)Wt;
#pragma unroll
        for (int i = 0; i < 8; ++i) {
            int c = tid + i * 256;
            int n = c >> 4, off = c & 15;
            int b = (n * 256 + off * 16) ^ ((n & 7) << 4);
            *(uint4*)((char*)WtS + b) = srcp[c];
        }
    }
    for (int t = blockIdx.x; t < ntiles; t += gridDim.x) {
        int rbase = t << 6;
        __syncthreads();
        {   // stage 64 H rows f32 -> bf16, swizzled
            const float4* H4 = (const float4*)(H + (size_t)rbase * DFEAT);
            int limrow = N - rbase;
#pragma unroll
            for (int i = 0; i < 4; ++i) {
                int c = tid + i * 256;
                int m = c >> 4, off = c & 15;
                uint4 w2 = make_uint4(0u, 0u, 0u, 0u);
                if (m < limrow) {
                    float4 f0 = H4[m * 32 + off * 2];
                    float4 f1 = H4[m * 32 + off * 2 + 1];
                    w2.x = packbf2(f0.x, f0.y); w2.y = packbf2(f0.z, f0.w);
                    w2.z = packbf2(f1.x, f1.y); w2.w = packbf2(f1.z, f1.w);
                }
                int b = (m * 256 + off * 16) ^ ((m & 7) << 4);
                *(uint4*)((char*)inS + b) = w2;
            }
        }
        __syncthreads();
        f32x4 acc[8];
#pragma unroll
        for (int nt = 0; nt < 8; ++nt) acc[nt] = (f32x4){0.f, 0.f, 0.f, 0.f};
        int mrow = wv * 16 + r;
        const char* inB = (const char*)inS + mrow * 256;
#pragma unroll
        for (int kk = 0; kk < 4; ++kk) {
            int koff = (kk * 64 + g * 16) ^ swz;
            bf16x8 bfrag = *(const bf16x8*)(inB + koff);
#pragma unroll
            for (int nt = 0; nt < 8; ++nt) {
                bf16x8 afrag = *(const bf16x8*)((const char*)WtS + (nt * 16 + r) * 256 + koff);
                acc[nt] = __builtin_amdgcn_mfma_f32_16x16x32_bf16(afrag, bfrag, acc[nt], 0, 0, 0);
            }
        }
        int m = rbase + mrow;
        if (m < N) {
            uint2* Crow = (uint2*)(C + (size_t)m * 64);
#pragma unroll
            for (int nt = 0; nt < 8; ++nt) {
                uint2 u;
                u.x = packbf2(acc[nt].x, acc[nt].y);
                u.y = packbf2(acc[nt].z, acc[nt].w);
                Crow[nt * 4 + g] = u;
            }
        }
    }
}

// Layer-2 linear: input already bf16-packed rows (16 uint4 per 256B row).
__global__ __launch_bounds__(256, 3) void k_linear_mfma_b16(const uint4* __restrict__ Hb,
                                                            const uint32* __restrict__ Wt,
                                                            uint32* __restrict__ C,
                                                            int N, int ntiles) {
    __shared__ uint32 WtS[128 * 64];  // 32 KB
    __shared__ uint32 inS[64 * 64];   // 16 KB
    int tid = threadIdx.x;
    int lane = tid & 63;
    int wv = tid >> 6;
    int g = lane >> 4;
    int r = lane & 15;
    int swz = (r & 7) << 4;
    {
        const uint4* srcp = (const uint4*)Wt;
#pragma unroll
        for (int i = 0; i < 8; ++i) {
            int c = tid + i * 256;
            int n = c >> 4, off = c & 15;
            int b = (n * 256 + off * 16) ^ ((n & 7) << 4);
            *(uint4*)((char*)WtS + b) = srcp[c];
        }
    }
    for (int t = blockIdx.x; t < ntiles; t += gridDim.x) {
        int rbase = t << 6;
        __syncthreads();
        {   // stage 64 bf16 rows: straight copy, swizzled
            int limrow = N - rbase;
#pragma unroll
            for (int i = 0; i < 4; ++i) {
                int c = tid + i * 256;        // 0..1023
                int m = c >> 4, off = c & 15;
                uint4 v = make_uint4(0u, 0u, 0u, 0u);
                if (m < limrow) v = Hb[(size_t)(rbase + m) * 16 + off];
                int b = (m * 256 + off * 16) ^ ((m & 7) << 4);
                *(uint4*)((char*)inS + b) = v;
            }
        }
        __syncthreads();
        f32x4 acc[8];
#pragma unroll
        for (int nt = 0; nt < 8; ++nt) acc[nt] = (f32x4){0.f, 0.f, 0.f, 0.f};
        int mrow = wv * 16 + r;
        const char* inB = (const char*)inS + mrow * 256;
#pragma unroll
        for (int kk = 0; kk < 4; ++kk) {
            int koff = (kk * 64 + g * 16) ^ swz;
            bf16x8 bfrag = *(const bf16x8*)(inB + koff);
#pragma unroll
            for (int nt = 0; nt < 8; ++nt) {
                bf16x8 afrag = *(const bf16x8*)((const char*)WtS + (nt * 16 + r) * 256 + koff);
                acc[nt] = __builtin_amdgcn_mfma_f32_16x16x32_bf16(afrag, bfrag, acc[nt], 0, 0, 0);
            }
        }
        int m = rbase + mrow;
        if (m < N) {
            uint2* Crow = (uint2*)(C + (size_t)m * 64);
#pragma unroll
            for (int nt = 0; nt < 8; ++nt) {
                uint2 u;
                u.x = packbf2(acc[nt].x, acc[nt].y);
                u.y = packbf2(acc[nt].z, acc[nt].w);
                Crow[nt * 4 + g] = u;
            }
        }
    }
}

// Pull aggregation (R11 form) with bf16 OUTPUT (R16): wave per node, lane
// holds feats 2l,2l+1; x4 unroll; f32 accum; packed bf16 write.
__global__ __launch_bounds__(256) void k_agg(const uint32* __restrict__ Tb,
                                             uint32* __restrict__ Bout,
                                             const int* __restrict__ col,
                                             const int* __restrict__ rowptr,
                                             const float* __restrict__ dinv,
                                             const float* __restrict__ bias, int N) {
    int lane = threadIdx.x & 63;
    int node = blockIdx.x * 4 + (threadIdx.x >> 6);
    if (node >= N) return;
    float2 b = ((const float2*)bias)[lane];
    float di = dinv[node];
    uint32 us = Tb[(size_t)node * 64 + lane];
    float ws = di * di;
    float2 acc;
    acc.x = bflo(us) * ws;
    acc.y = bfhi(us) * ws;
    int beg = rowptr[node], end = rowptr[node + 1];
    int j = beg;
    for (; j + 3 < end; j += 4) {
        int s0 = col[j + 0];
        int s1 = col[j + 1];
        int s2 = col[j + 2];
        int s3 = col[j + 3];
        float w0 = dinv[s0] * di;
        float w1 = dinv[s1] * di;
        float w2 = dinv[s2] * di;
        float w3 = dinv[s3] * di;
        uint32 u0 = Tb[(size_t)s0 * 64 + lane];
        uint32 u1 = Tb[(size_t)s1 * 64 + lane];
        uint32 u2 = Tb[(size_t)s2 * 64 + lane];
        uint32 u3 = Tb[(size_t)s3 * 64 + lane];
        acc.x += w0 * bflo(u0); acc.y += w0 * bfhi(u0);
        acc.x += w1 * bflo(u1); acc.y += w1 * bfhi(u1);
        acc.x += w2 * bflo(u2); acc.y += w2 * bfhi(u2);
        acc.x += w3 * bflo(u3); acc.y += w3 * bfhi(u3);
    }
    for (; j < end; ++j) {
        int s = col[j];
        float w = dinv[s] * di;
        uint32 u = Tb[(size_t)s * 64 + lane];
        acc.x += w * bflo(u);
        acc.y += w * bfhi(u);
    }
    float ox = fmaxf(acc.x + b.x, 0.f);
    float oy = fmaxf(acc.y + b.y, 0.f);
    Bout[(size_t)node * 64 + lane] = packbf2(ox, oy);
}

// Pool phase 1: bf16 input, wave-sliced partial sums, atomic flush at
// graph boundaries.
__global__ __launch_bounds__(256) void k_pool_sum(const uint32* __restrict__ Hn,
                                                  const int* __restrict__ batch,
                                                  float* __restrict__ gsum,
                                                  int N, int waves_total) {
    int w = blockIdx.x * 4 + (threadIdx.x >> 6);
    int lane = threadIdx.x & 63;
    int per = (N + waves_total - 1) / waves_total;
    int n0 = w * per;
    int n1 = min(N, n0 + per);
    if (n0 >= n1) return;
    int gcur = batch[n0];
    float2 acc = make_float2(0.f, 0.f);
    for (int i = n0; i < n1; ++i) {
        int g = batch[i];
        if (g != gcur) {
            atomicAdd(&gsum[gcur * DFEAT + lane * 2 + 0], acc.x);
            atomicAdd(&gsum[gcur * DFEAT + lane * 2 + 1], acc.y);
            acc = make_float2(0.f, 0.f);
            gcur = g;
        }
        uint32 v = Hn[(size_t)i * 64 + lane];
        acc.x += bflo(v);
        acc.y += bfhi(v);
    }
    atomicAdd(&gsum[gcur * DFEAT + lane * 2 + 0], acc.x);
    atomicAdd(&gsum[gcur * DFEAT + lane * 2 + 1], acc.y);
}

// Pool phase 2: divide by count, dot Wf, +bf.
__global__ __launch_bounds__(128) void k_head(const float* __restrict__ gsum,
                                              const int* __restrict__ batch,
                                              const float* __restrict__ Wf,
                                              const float* __restrict__ bf,
                                              float* __restrict__ out, int N) {
    int g = blockIdx.x;
    int tid = threadIdx.x;
    int l = 0, h = N;
    while (l < h) { int m = (l + h) >> 1; if (batch[m] < g) l = m + 1; else h = m; }
    int lo = l;
    h = N;
    while (l < h) { int m = (l + h) >> 1; if (batch[m] < g + 1) l = m + 1; else h = m; }
    int hi = l;
    float cnt = (float)((hi - lo) > 0 ? (hi - lo) : 1);
    float val = (gsum[g * DFEAT + tid] / cnt) * Wf[tid];
    for (int off = 32; off >= 1; off >>= 1) val += __shfl_down(val, off, 64);
    __shared__ float ws2[2];
    if ((tid & 63) == 0) ws2[tid >> 6] = val;
    __syncthreads();
    if (tid == 0) out[g] = ws2[0] + ws2[1] + bf[0];
}

extern "C" void kernel_launch(void* const* d_in, const int* in_sizes, int n_in,
                              void* d_out, int out_size, void* d_ws, size_t ws_size,
                              hipStream_t stream) {
    const float* x    = (const float*)d_in[0];
    const int*   ei   = (const int*)d_in[1];
    const int*   batch= (const int*)d_in[2];
    const float* W1   = (const float*)d_in[3];
    const float* b1   = (const float*)d_in[4];
    const float* W2   = (const float*)d_in[5];
    const float* b2   = (const float*)d_in[6];
    const float* Wf   = (const float*)d_in[7];
    const float* bf   = (const float*)d_in[8];

    int N = in_sizes[0] / DFEAT;
    int E = in_sizes[1] / 2;
    int G = out_size;  // num_graphs

    const int* src = ei;
    const int* dst = ei + E;

    char* wsb = (char*)d_ws;
    size_t off = 0;
    auto walloc = [&](size_t bytes) {
        void* p = wsb + off;
        off = (off + bytes + 255) & ~(size_t)255;
        return p;
    };
    uint32* A     = (uint32*)walloc((size_t)N * 64 * sizeof(uint32)); // bf16 linear out, 25.6 MB
    uint32* B     = (uint32*)walloc((size_t)N * 64 * sizeof(uint32)); // bf16 agg out, 25.6 MB
    float* dinv   = (float*)walloc((size_t)N * sizeof(float));
    int*   rowptr = (int*)  walloc((size_t)(N + 1) * sizeof(int));
    int*   col    = (int*)  walloc((size_t)E * sizeof(int));           // 6.4 MB
    int*   degcnt = (int*)  walloc((size_t)N * sizeof(int));
    int*   fill   = (int*)  walloc((size_t)N * sizeof(int));
    float* gsum   = (float*)walloc((size_t)G * DFEAT * sizeof(float)); // 32 KB
    int*   bsum   = (int*)  walloc((size_t)SCAN_NB * sizeof(int));
    unsigned short* Wt1 = (unsigned short*)walloc(128 * 128 * sizeof(unsigned short));
    unsigned short* Wt2 = (unsigned short*)walloc(128 * 128 * sizeof(unsigned short));
    (void)ws_size; (void)n_in;

    int gN = (N + 255) / 256;
    int gE = (E + 255) / 256;
    int chunk = (N + SCAN_NB - 1) / SCAN_NB;
    int ntiles = (N + 63) >> 6;

    // CSR build + weight transposes
    k_zero2<<<gN, 256, 0, stream>>>(degcnt, fill, N);
    k_zero_f<<<(G * DFEAT + 255) / 256, 256, 0, stream>>>(gsum, G * DFEAT);
    k_wt<<<64, 256, 0, stream>>>(W1, Wt1);
    k_wt<<<64, 256, 0, stream>>>(W2, Wt2);
    k_degcount<<<gE, 256, 0, stream>>>(dst, degcnt, E);
    k_partsum<<<SCAN_NB, SCAN_TPB, 0, stream>>>(degcnt, bsum, N, chunk);
    k_scanb<<<1, SCAN_NB, 0, stream>>>(bsum);
    k_writeptr<<<SCAN_NB, SCAN_TPB, 0, stream>>>(degcnt, bsum, rowptr, dinv, N, chunk);
    k_fill<<<FILL_CHUNKS * 8, 256, 0, stream>>>(src, dst, rowptr, fill, col, E);

    // layer 1
    k_linear_mfma<<<768, 256, 0, stream>>>(x, (const uint32*)Wt1, A, N, ntiles);
    k_agg<<<(N + 3) / 4, 256, 0, stream>>>(A, B, col, rowptr, dinv, b1, N);
    // layer 2
    k_linear_mfma_b16<<<768, 256, 0, stream>>>((const uint4*)B, (const uint32*)Wt2, A, N, ntiles);
    k_agg<<<(N + 3) / 4, 256, 0, stream>>>(A, B, col, rowptr, dinv, b2, N);

    // pool + head
    const int POOL_BLOCKS = 1024;
    k_pool_sum<<<POOL_BLOCKS, 256, 0, stream>>>(B, batch, gsum, N, POOL_BLOCKS * 4);
    k_head<<<G, 128, 0, stream>>>(gsum, batch, Wf, bf, (float*)d_out, N);
}

// Round 17
// 345.905 us; speedup vs baseline: 2.2206x; 1.0427x over previous
//
#include <hip/hip_runtime.h>
#include <hip/hip_bf16.h>
#include <math.h>

// GCN: h1 = relu(Agg(x@W1) + b1); h2 = relu(Agg(h1@W2) + b2);
// out[g] = mean_pool(h2)[g] @ Wf + bf
// R4: wave-sliced pool. R5: decoupled scan. R6: k_agg unroll x4.
// R7: bf16 feature table. R8: k_fill %8-role partition. R9/R10: MFMA linear.
// R13/R14/R15: lane-split agg, NT loads, XCD ticketing all regressed -> reverted.
// R16: bf16 B buffer (agg out / linear-2 in / pool in). 360.7us.
// R17: k_agg unroll 4->8. MLP math: 22 waves/CU x 4 x 256B = 22KB in flight
//   at ~375ns miss latency = 3.0 TB/s = measured -> latency*MLP bound, not
//   fabric. 8 gathers in flight should reach ~4 TB/s.

#define DFEAT 128
#define SCAN_NB 256
#define SCAN_TPB 256
#define FILL_CHUNKS 256

typedef unsigned int uint32;
typedef __attribute__((ext_vector_type(8))) short bf16x8;
typedef __attribute__((ext_vector_type(4))) float f32x4;

__device__ __forceinline__ uint32 f2bf_rne(float f) {
    uint32 x = __float_as_uint(f);
    return (x + 0x7fffu + ((x >> 16) & 1u)) >> 16;
}
__device__ __forceinline__ uint32 packbf2(float lo, float hi) {
    return f2bf_rne(lo) | (f2bf_rne(hi) << 16);
}
__device__ __forceinline__ float bflo(uint32 u) { return __uint_as_float(u << 16); }
__device__ __forceinline__ float bfhi(uint32 u) { return __uint_as_float(u & 0xffff0000u); }

__global__ void k_zero2(int* __restrict__ a, int* __restrict__ b, int n) {
    int i = blockIdx.x * blockDim.x + threadIdx.x;
    if (i < n) { a[i] = 0; b[i] = 0; }
}

__global__ void k_zero_f(float* __restrict__ p, int n) {
    int i = blockIdx.x * blockDim.x + threadIdx.x;
    if (i < n) p[i] = 0.f;
}

__global__ void k_degcount(const int* __restrict__ dst, int* __restrict__ degcnt, int E) {
    int e = blockIdx.x * blockDim.x + threadIdx.x;
    if (e < E) atomicAdd(&degcnt[dst[e]], 1);
}

// W[k][n] f32 -> Wt[n][k] bf16 (one-time, 16K elements)
__global__ __launch_bounds__(256) void k_wt(const float* __restrict__ W,
                                            unsigned short* __restrict__ Wt) {
    int idx = blockIdx.x * 256 + threadIdx.x;
    if (idx < 128 * 128) {
        int n = idx >> 7, k = idx & 127;
        Wt[idx] = (unsigned short)f2bf_rne(W[(k << 7) + n]);
    }
}

// Scan phase 1
__global__ __launch_bounds__(SCAN_TPB) void k_partsum(const int* __restrict__ deg,
                                                      int* __restrict__ bsum,
                                                      int N, int chunk) {
    int b = blockIdx.x, tid = threadIdx.x;
    int beg = b * chunk, end = min(N, beg + chunk);
    int s = 0;
    for (int i = beg + tid; i < end; i += SCAN_TPB) s += deg[i];
    __shared__ int lds[SCAN_TPB];
    lds[tid] = s;
    __syncthreads();
    for (int off = SCAN_TPB / 2; off > 0; off >>= 1) {
        if (tid < off) lds[tid] += lds[tid + off];
        __syncthreads();
    }
    if (tid == 0) bsum[b] = lds[0];
}

// Scan phase 2
__global__ __launch_bounds__(SCAN_NB) void k_scanb(int* __restrict__ bsum) {
    __shared__ int lds[SCAN_NB];
    int tid = threadIdx.x;
    int v = bsum[tid];
    lds[tid] = v;
    __syncthreads();
    for (int off = 1; off < SCAN_NB; off <<= 1) {
        int t = (tid >= off) ? lds[tid - off] : 0;
        __syncthreads();
        lds[tid] += t;
        __syncthreads();
    }
    bsum[tid] = lds[tid] - v;  // exclusive base
}

// Scan phase 3: write rowptr + dinv
__global__ __launch_bounds__(SCAN_TPB) void k_writeptr(const int* __restrict__ deg,
                                                       const int* __restrict__ bbase,
                                                       int* __restrict__ rowptr,
                                                       float* __restrict__ dinv,
                                                       int N, int chunk) {
    int b = blockIdx.x, tid = threadIdx.x;
    int beg = b * chunk, end = min(N, beg + chunk);
    int per = (chunk + SCAN_TPB - 1) / SCAN_TPB;
    int tbeg = beg + tid * per;
    int tend = min(end, tbeg + per);
    int s = 0;
    for (int i = tbeg; i < tend; ++i) s += deg[i];
    __shared__ int lds[SCAN_TPB];
    lds[tid] = s;
    __syncthreads();
    for (int off = 1; off < SCAN_TPB; off <<= 1) {
        int t = (tid >= off) ? lds[tid - off] : 0;
        __syncthreads();
        lds[tid] += t;
        __syncthreads();
    }
    int run = bbase[b] + ((tid == 0) ? 0 : lds[tid - 1]);
    for (int i = tbeg; i < tend; ++i) {
        int d = deg[i];
        rowptr[i] = run;
        dinv[i] = rsqrtf((float)(d + 1));  // +1 self-loop
        run += d;
    }
    if (tend == N && tbeg < tend) rowptr[N] = run;  // == E
}

// CSR fill, %8-role partitioned (R8/R11 proven form).
__global__ __launch_bounds__(256) void k_fill(const int* __restrict__ src,
                                              const int* __restrict__ dst,
                                              const int* __restrict__ rowptr,
                                              int* __restrict__ fill,
                                              int* __restrict__ col, int E) {
    int r = blockIdx.x & 7;
    int chunk = blockIdx.x >> 3;
    int per = (E + FILL_CHUNKS - 1) / FILL_CHUNKS;
    int beg = chunk * per;
    int end = min(E, beg + per);
    for (int e = beg + threadIdx.x; e < end; e += 256) {
        int d = dst[e];
        if (((d >> 9) & 7) == r) {
            int pos = rowptr[d] + atomicAdd(&fill[d], 1);
            col[pos] = src[e];
        }
    }
}

// Layer-1 linear: C[N,128](bf16) = H[N,128](f32) @ Wt. MFMA 16x16x32.
__global__ __launch_bounds__(256, 3) void k_linear_mfma(const float* __restrict__ H,
                                                        const uint32* __restrict__ Wt,
                                                        uint32* __restrict__ C,
                                                        int N, int ntiles) {
    __shared__ uint32 WtS[128 * 64];  // 32 KB
    __shared__ uint32 inS[64 * 64];   // 16 KB
    int tid = threadIdx.x;
    int lane = tid & 63;
    int wv = tid >> 6;
    int g = lane >> 4;
    int r = lane & 15;
    int swz = (r & 7) << 4;
    {   // stage Wt -> LDS: 2048 uint4 chunks, 16 per 256B row
        const uint4* srcp = (const uint4*)Wt;
#pragma unroll
        for (int i = 0; i < 8; ++i) {
            int c = tid + i * 256;
            int n = c >> 4, off = c & 15;
            int b = (n * 256 + off * 16) ^ ((n & 7) << 4);
            *(uint4*)((char*)WtS + b) = srcp[c];
        }
    }
    for (int t = blockIdx.x; t < ntiles; t += gridDim.x) {
        int rbase = t << 6;
        __syncthreads();
        {   // stage 64 H rows f32 -> bf16, swizzled
            const float4* H4 = (const float4*)(H + (size_t)rbase * DFEAT);
            int limrow = N - rbase;
#pragma unroll
            for (int i = 0; i < 4; ++i) {
                int c = tid + i * 256;
                int m = c >> 4, off = c & 15;
                uint4 w2 = make_uint4(0u, 0u, 0u, 0u);
                if (m < limrow) {
                    float4 f0 = H4[m * 32 + off * 2];
                    float4 f1 = H4[m * 32 + off * 2 + 1];
                    w2.x = packbf2(f0.x, f0.y); w2.y = packbf2(f0.z, f0.w);
                    w2.z = packbf2(f1.x, f1.y); w2.w = packbf2(f1.z, f1.w);
                }
                int b = (m * 256 + off * 16) ^ ((m & 7) << 4);
                *(uint4*)((char*)inS + b) = w2;
            }
        }
        __syncthreads();
        f32x4 acc[8];
#pragma unroll
        for (int nt = 0; nt < 8; ++nt) acc[nt] = (f32x4){0.f, 0.f, 0.f, 0.f};
        int mrow = wv * 16 + r;
        const char* inB = (const char*)inS + mrow * 256;
#pragma unroll
        for (int kk = 0; kk < 4; ++kk) {
            int koff = (kk * 64 + g * 16) ^ swz;
            bf16x8 bfrag = *(const bf16x8*)(inB + koff);
#pragma unroll
            for (int nt = 0; nt < 8; ++nt) {
                bf16x8 afrag = *(const bf16x8*)((const char*)WtS + (nt * 16 + r) * 256 + koff);
                acc[nt] = __builtin_amdgcn_mfma_f32_16x16x32_bf16(afrag, bfrag, acc[nt], 0, 0, 0);
            }
        }
        int m = rbase + mrow;
        if (m < N) {
            uint2* Crow = (uint2*)(C + (size_t)m * 64);
#pragma unroll
            for (int nt = 0; nt < 8; ++nt) {
                uint2 u;
                u.x = packbf2(acc[nt].x, acc[nt].y);
                u.y = packbf2(acc[nt].z, acc[nt].w);
                Crow[nt * 4 + g] = u;
            }
        }
    }
}

// Layer-2 linear: input already bf16-packed rows (16 uint4 per 256B row).
__global__ __launch_bounds__(256, 3) void k_linear_mfma_b16(const uint4* __restrict__ Hb,
                                                            const uint32* __restrict__ Wt,
                                                            uint32* __restrict__ C,
                                                            int N, int ntiles) {
    __shared__ uint32 WtS[128 * 64];  // 32 KB
    __shared__ uint32 inS[64 * 64];   // 16 KB
    int tid = threadIdx.x;
    int lane = tid & 63;
    int wv = tid >> 6;
    int g = lane >> 4;
    int r = lane & 15;
    int swz = (r & 7) << 4;
    {
        const uint4* srcp = (const uint4*)Wt;
#pragma unroll
        for (int i = 0; i < 8; ++i) {
            int c = tid + i * 256;
            int n = c >> 4, off = c & 15;
            int b = (n * 256 + off * 16) ^ ((n & 7) << 4);
            *(uint4*)((char*)WtS + b) = srcp[c];
        }
    }
    for (int t = blockIdx.x; t < ntiles; t += gridDim.x) {
        int rbase = t << 6;
        __syncthreads();
        {   // stage 64 bf16 rows: straight copy, swizzled
            int limrow = N - rbase;
#pragma unroll
            for (int i = 0; i < 4; ++i) {
                int c = tid + i * 256;        // 0..1023
                int m = c >> 4, off = c & 15;
                uint4 v = make_uint4(0u, 0u, 0u, 0u);
                if (m < limrow) v = Hb[(size_t)(rbase + m) * 16 + off];
                int b = (m * 256 + off * 16) ^ ((m & 7) << 4);
                *(uint4*)((char*)inS + b) = v;
            }
        }
        __syncthreads();
        f32x4 acc[8];
#pragma unroll
        for (int nt = 0; nt < 8; ++nt) acc[nt] = (f32x4){0.f, 0.f, 0.f, 0.f};
        int mrow = wv * 16 + r;
        const char* inB = (const char*)inS + mrow * 256;
#pragma unroll
        for (int kk = 0; kk < 4; ++kk) {
            int koff = (kk * 64 + g * 16) ^ swz;
            bf16x8 bfrag = *(const bf16x8*)(inB + koff);
#pragma unroll
            for (int nt = 0; nt < 8; ++nt) {
                bf16x8 afrag = *(const bf16x8*)((const char*)WtS + (nt * 16 + r) * 256 + koff);
                acc[nt] = __builtin_amdgcn_mfma_f32_16x16x32_bf16(afrag, bfrag, acc[nt], 0, 0, 0);
            }
        }
        int m = rbase + mrow;
        if (m < N) {
            uint2* Crow = (uint2*)(C + (size_t)m * 64);
#pragma unroll
            for (int nt = 0; nt < 8; ++nt) {
                uint2 u;
                u.x = packbf2(acc[nt].x, acc[nt].y);
                u.y = packbf2(acc[nt].z, acc[nt].w);
                Crow[nt * 4 + g] = u;
            }
        }
    }
}

// Pull aggregation, R17: unroll 8 (8 independent gathers in flight per wave);
// wave per node, lane holds feats 2l,2l+1; f32 accum; bf16 out.
__global__ __launch_bounds__(256) void k_agg(const uint32* __restrict__ Tb,
                                             uint32* __restrict__ Bout,
                                             const int* __restrict__ col,
                                             const int* __restrict__ rowptr,
                                             const float* __restrict__ dinv,
                                             const float* __restrict__ bias, int N) {
    int lane = threadIdx.x & 63;
    int node = blockIdx.x * 4 + (threadIdx.x >> 6);
    if (node >= N) return;
    float2 b = ((const float2*)bias)[lane];
    float di = dinv[node];
    uint32 us = Tb[(size_t)node * 64 + lane];
    float ws = di * di;
    float2 acc;
    acc.x = bflo(us) * ws;
    acc.y = bfhi(us) * ws;
    int beg = rowptr[node], end = rowptr[node + 1];
    int j = beg;
    for (; j + 7 < end; j += 8) {
        int s0 = col[j + 0];
        int s1 = col[j + 1];
        int s2 = col[j + 2];
        int s3 = col[j + 3];
        int s4 = col[j + 4];
        int s5 = col[j + 5];
        int s6 = col[j + 6];
        int s7 = col[j + 7];
        float w0 = dinv[s0] * di;
        float w1 = dinv[s1] * di;
        float w2 = dinv[s2] * di;
        float w3 = dinv[s3] * di;
        float w4 = dinv[s4] * di;
        float w5 = dinv[s5] * di;
        float w6 = dinv[s6] * di;
        float w7 = dinv[s7] * di;
        uint32 u0 = Tb[(size_t)s0 * 64 + lane];
        uint32 u1 = Tb[(size_t)s1 * 64 + lane];
        uint32 u2 = Tb[(size_t)s2 * 64 + lane];
        uint32 u3 = Tb[(size_t)s3 * 64 + lane];
        uint32 u4 = Tb[(size_t)s4 * 64 + lane];
        uint32 u5 = Tb[(size_t)s5 * 64 + lane];
        uint32 u6 = Tb[(size_t)s6 * 64 + lane];
        uint32 u7 = Tb[(size_t)s7 * 64 + lane];
        acc.x += w0 * bflo(u0); acc.y += w0 * bfhi(u0);
        acc.x += w1 * bflo(u1); acc.y += w1 * bfhi(u1);
        acc.x += w2 * bflo(u2); acc.y += w2 * bfhi(u2);
        acc.x += w3 * bflo(u3); acc.y += w3 * bfhi(u3);
        acc.x += w4 * bflo(u4); acc.y += w4 * bfhi(u4);
        acc.x += w5 * bflo(u5); acc.y += w5 * bfhi(u5);
        acc.x += w6 * bflo(u6); acc.y += w6 * bfhi(u6);
        acc.x += w7 * bflo(u7); acc.y += w7 * bfhi(u7);
    }
    for (; j + 3 < end; j += 4) {
        int s0 = col[j + 0];
        int s1 = col[j + 1];
        int s2 = col[j + 2];
        int s3 = col[j + 3];
        float w0 = dinv[s0] * di;
        float w1 = dinv[s1] * di;
        float w2 = dinv[s2] * di;
        float w3 = dinv[s3] * di;
        uint32 u0 = Tb[(size_t)s0 * 64 + lane];
        uint32 u1 = Tb[(size_t)s1 * 64 + lane];
        uint32 u2 = Tb[(size_t)s2 * 64 + lane];
        uint32 u3 = Tb[(size_t)s3 * 64 + lane];
        acc.x += w0 * bflo(u0); acc.y += w0 * bfhi(u0);
        acc.x += w1 * bflo(u1); acc.y += w1 * bfhi(u1);
        acc.x += w2 * bflo(u2); acc.y += w2 * bfhi(u2);
        acc.x += w3 * bflo(u3); acc.y += w3 * bfhi(u3);
    }
    for (; j < end; ++j) {
        int s = col[j];
        float w = dinv[s] * di;
        uint32 u = Tb[(size_t)s * 64 + lane];
        acc.x += w * bflo(u);
        acc.y += w * bfhi(u);
    }
    float ox = fmaxf(acc.x + b.x, 0.f);
    float oy = fmaxf(acc.y + b.y, 0.f);
    Bout[(size_t)node * 64 + lane] = packbf2(ox, oy);
}

// Pool phase 1: bf16 input, wave-sliced partial sums, atomic flush at
// graph boundaries.
__global__ __launch_bounds__(256) void k_pool_sum(const uint32* __restrict__ Hn,
                                                  const int* __restrict__ batch,
                                                  float* __restrict__ gsum,
                                                  int N, int waves_total) {
    int w = blockIdx.x * 4 + (threadIdx.x >> 6);
    int lane = threadIdx.x & 63;
    int per = (N + waves_total - 1) / waves_total;
    int n0 = w * per;
    int n1 = min(N, n0 + per);
    if (n0 >= n1) return;
    int gcur = batch[n0];
    float2 acc = make_float2(0.f, 0.f);
    for (int i = n0; i < n1; ++i) {
        int g = batch[i];
        if (g != gcur) {
            atomicAdd(&gsum[gcur * DFEAT + lane * 2 + 0], acc.x);
            atomicAdd(&gsum[gcur * DFEAT + lane * 2 + 1], acc.y);
            acc = make_float2(0.f, 0.f);
            gcur = g;
        }
        uint32 v = Hn[(size_t)i * 64 + lane];
        acc.x += bflo(v);
        acc.y += bfhi(v);
    }
    atomicAdd(&gsum[gcur * DFEAT + lane * 2 + 0], acc.x);
    atomicAdd(&gsum[gcur * DFEAT + lane * 2 + 1], acc.y);
}

// Pool phase 2: divide by count, dot Wf, +bf.
__global__ __launch_bounds__(128) void k_head(const float* __restrict__ gsum,
                                              const int* __restrict__ batch,
                                              const float* __restrict__ Wf,
                                              const float* __restrict__ bf,
                                              float* __restrict__ out, int N) {
    int g = blockIdx.x;
    int tid = threadIdx.x;
    int l = 0, h = N;
    while (l < h) { int m = (l + h) >> 1; if (batch[m] < g) l = m + 1; else h = m; }
    int lo = l;
    h = N;
    while (l < h) { int m = (l + h) >> 1; if (batch[m] < g + 1) l = m + 1; else h = m; }
    int hi = l;
    float cnt = (float)((hi - lo) > 0 ? (hi - lo) : 1);
    float val = (gsum[g * DFEAT + tid] / cnt) * Wf[tid];
    for (int off = 32; off >= 1; off >>= 1) val += __shfl_down(val, off, 64);
    __shared__ float ws2[2];
    if ((tid & 63) == 0) ws2[tid >> 6] = val;
    __syncthreads();
    if (tid == 0) out[g] = ws2[0] + ws2[1] + bf[0];
}

extern "C" void kernel_launch(void* const* d_in, const int* in_sizes, int n_in,
                              void* d_out, int out_size, void* d_ws, size_t ws_size,
                              hipStream_t stream) {
    const float* x    = (const float*)d_in[0];
    const int*   ei   = (const int*)d_in[1];
    const int*   batch= (const int*)d_in[2];
    const float* W1   = (const float*)d_in[3];
    const float* b1   = (const float*)d_in[4];
    const float* W2   = (const float*)d_in[5];
    const float* b2   = (const float*)d_in[6];
    const float* Wf   = (const float*)d_in[7];
    const float* bf   = (const float*)d_in[8];

    int N = in_sizes[0] / DFEAT;
    int E = in_sizes[1] / 2;
    int G = out_size;  // num_graphs

    const int* src = ei;
    const int* dst = ei + E;

    char* wsb = (char*)d_ws;
    size_t off = 0;
    auto walloc = [&](size_t bytes) {
        void* p = wsb + off;
        off = (off + bytes + 255) & ~(size_t)255;
        return p;
    };
    uint32* A     = (uint32*)walloc((size_t)N * 64 * sizeof(uint32)); // bf16 linear out, 25.6 MB
    uint32* B     = (uint32*)walloc((size_t)N * 64 * sizeof(uint32)); // bf16 agg out, 25.6 MB
    float* dinv   = (float*)walloc((size_t)N * sizeof(float));
    int*   rowptr = (int*)  walloc((size_t)(N + 1) * sizeof(int));
    int*   col    = (int*)  walloc((size_t)E * sizeof(int));           // 6.4 MB
    int*   degcnt = (int*)  walloc((size_t)N * sizeof(int));
    int*   fill   = (int*)  walloc((size_t)N * sizeof(int));
    float* gsum   = (float*)walloc((size_t)G * DFEAT * sizeof(float)); // 32 KB
    int*   bsum   = (int*)  walloc((size_t)SCAN_NB * sizeof(int));
    unsigned short* Wt1 = (unsigned short*)walloc(128 * 128 * sizeof(unsigned short));
    unsigned short* Wt2 = (unsigned short*)walloc(128 * 128 * sizeof(unsigned short));
    (void)ws_size; (void)n_in;

    int gN = (N + 255) / 256;
    int gE = (E + 255) / 256;
    int chunk = (N + SCAN_NB - 1) / SCAN_NB;
    int ntiles = (N + 63) >> 6;

    // CSR build + weight transposes
    k_zero2<<<gN, 256, 0, stream>>>(degcnt, fill, N);
    k_zero_f<<<(G * DFEAT + 255) / 256, 256, 0, stream>>>(gsum, G * DFEAT);
    k_wt<<<64, 256, 0, stream>>>(W1, Wt1);
    k_wt<<<64, 256, 0, stream>>>(W2, Wt2);
    k_degcount<<<gE, 256, 0, stream>>>(dst, degcnt, E);
    k_partsum<<<SCAN_NB, SCAN_TPB, 0, stream>>>(degcnt, bsum, N, chunk);
    k_scanb<<<1, SCAN_NB, 0, stream>>>(bsum);
    k_writeptr<<<SCAN_NB, SCAN_TPB, 0, stream>>>(degcnt, bsum, rowptr, dinv, N, chunk);
    k_fill<<<FILL_CHUNKS * 8, 256, 0, stream>>>(src, dst, rowptr, fill, col, E);

    // layer 1
    k_linear_mfma<<<768, 256, 0, stream>>>(x, (const uint32*)Wt1, A, N, ntiles);
    k_agg<<<(N + 3) / 4, 256, 0, stream>>>(A, B, col, rowptr, dinv, b1, N);
    // layer 2
    k_linear_mfma_b16<<<768, 256, 0, stream>>>((const uint4*)B, (const uint32*)Wt2, A, N, ntiles);
    k_agg<<<(N + 3) / 4, 256, 0, stream>>>(A, B, col, rowptr, dinv, b2, N);

    // pool + head
    const int POOL_BLOCKS = 1024;
    k_pool_sum<<<POOL_BLOCKS, 256, 0, stream>>>(B, batch, gsum, N, POOL_BLOCKS * 4);
    k_head<<<G, 128, 0, stream>>>(gsum, batch, Wf, bf, (float*)d_out, N);
}